// Round 5
// baseline (6123.962 us; speedup 1.0000x reference)
//
#include <hip/hip_runtime.h>
#include <hip/hip_bf16.h>
#include <stdint.h>

typedef _Float16 f16;
typedef _Float16 f16x8 __attribute__((ext_vector_type(8)));
typedef float f32x4 __attribute__((ext_vector_type(4)));

#define B_SZ 4096
#define HID  1024
#define LAT  128
#define OBS  64
#define TSEQ 70
#define SPLIT_SCALE 2048.0f        // 2^11
#define SPLIT_INV   (1.0f / 2048.0f)

// direct global->LDS, 16B per lane; LDS dest is wave-uniform base, HW adds lane*16
__device__ __forceinline__ void gl2lds16(const void* g, void* l) {
  __builtin_amdgcn_global_load_lds(
      (const __attribute__((address_space(1))) void*)g,
      (__attribute__((address_space(3))) void*)l, 16, 0, 0);
}

__device__ __forceinline__ float tanh_fast(float x) {
  float e = __expf(2.0f * x);          // inf-safe: x>>0 -> 1, x<<0 -> -1
  return 1.0f - 2.0f / (e + 1.0f);
}

// H = tanh(A @ W^T + bias), A,W in double-f16 (hi + lo*2^-11 ~ 22-bit capture):
//   acc0 = A0*W0 ; acc1 = A0*W1' + A1'*W0  (primes pre-scaled 2^11)
//   a = acc0 + acc1*2^-11   (dropped A1*W1 term is 2^-22 rel)
// R5: 64x64 tile, BK=32 -> grid 64x16 = 1024 blocks = 4 blocks/CU for
// block-level latency hiding. SINGLE-buffered LDS (16 KB), TWO barriers per
// K-iter (m97-pedigree structure: stage -> barrier -> compute -> barrier) —
// R4's double-buffered variant diverged on replay (suspected rare LDS race).
// LDS chunk c (16 rows x 32 k) is lane-linear 16B = exact 16x16x32 A/B frag.
// Waves 2x2: wave (wr,wc) computes rows [wr*32,+32) x cols [wc*32,+32).
__global__ __launch_bounds__(256, 4) void rnn_step_split(
    const f16* __restrict__ Ah, const f16* __restrict__ Al,
    const f16* __restrict__ Wh, const f16* __restrict__ Wl,
    const float* __restrict__ bias,
    f16* __restrict__ Hh, f16* __restrict__ Hl, int K)
{
  __shared__ __align__(16) f16 sAh[64 * 32];
  __shared__ __align__(16) f16 sAl[64 * 32];
  __shared__ __align__(16) f16 sWh[64 * 32];
  __shared__ __align__(16) f16 sWl[64 * 32];

  const int lane = threadIdx.x & 63;
  const int wave = threadIdx.x >> 6;
  const int bm = blockIdx.x;      // 64  (M/64)
  const int bn = blockIdx.y;      // 16  (1024/64)
  const int wr = wave >> 1;
  const int wc = wave & 1;
  const int sr = lane & 15;
  const int sq = lane >> 4;

  const f16* Ahb = Ah + (size_t)(bm * 64) * K;
  const f16* Alb = Al + (size_t)(bm * 64) * K;
  const f16* Whb = Wh + (size_t)(bn * 64) * K;
  const f16* Wlb = Wl + (size_t)(bn * 64) * K;

  f32x4 acc0[2][2], acc1[2][2];
  const f32x4 z4 = {0.f, 0.f, 0.f, 0.f};
#pragma unroll
  for (int i = 0; i < 2; ++i)
#pragma unroll
    for (int j = 0; j < 2; ++j) { acc0[i][j] = z4; acc1[i][j] = z4; }

  const int nk = K >> 5;

  for (int it = 0; it < nk; ++it) {
    // stage: wave w loads chunk w (rows [w*16,+16) x 32 k) of all 4 matrices
    {
      const size_t go = (size_t)(wave * 16 + sr) * K + (it << 5) + sq * 8;
      gl2lds16(Ahb + go, &sAh[wave * 512]);
      gl2lds16(Alb + go, &sAl[wave * 512]);
      gl2lds16(Whb + go, &sWh[wave * 512]);
      gl2lds16(Wlb + go, &sWl[wave * 512]);
    }
    __syncthreads();  // compiler drains vmcnt(0): all LDS writes landed

    f16x8 vah[2], val[2], vwh[2], vwl[2];
#pragma unroll
    for (int i = 0; i < 2; ++i) {
      vah[i] = *(const f16x8*)&sAh[(wr * 2 + i) * 512 + lane * 8];
      val[i] = *(const f16x8*)&sAl[(wr * 2 + i) * 512 + lane * 8];
      vwh[i] = *(const f16x8*)&sWh[(wc * 2 + i) * 512 + lane * 8];
      vwl[i] = *(const f16x8*)&sWl[(wc * 2 + i) * 512 + lane * 8];
    }
#pragma unroll
    for (int i = 0; i < 2; ++i)
#pragma unroll
      for (int j = 0; j < 2; ++j) {
        acc0[i][j] = __builtin_amdgcn_mfma_f32_16x16x32_f16(vah[i], vwh[j], acc0[i][j], 0, 0, 0);
        acc1[i][j] = __builtin_amdgcn_mfma_f32_16x16x32_f16(vah[i], vwl[j], acc1[i][j], 0, 0, 0);
        acc1[i][j] = __builtin_amdgcn_mfma_f32_16x16x32_f16(val[i], vwh[j], acc1[i][j], 0, 0, 0);
      }
    __syncthreads();  // all ds_reads done before next stage overwrites
  }

  // C/D layout: col=lane&15, row=(lane>>4)*4+reg  [m89-verified]
  const int rq = lane >> 4;
  const int cl = lane & 15;
#pragma unroll
  for (int j = 0; j < 2; ++j) {
    const int gcol = bn * 64 + wc * 32 + j * 16 + cl;
    const float bb = bias[gcol];
#pragma unroll
    for (int i = 0; i < 2; ++i) {
      const int grow = bm * 64 + wr * 32 + i * 16 + rq * 4;
#pragma unroll
      for (int r = 0; r < 4; ++r) {
        const float a = acc0[i][j][r] + acc1[i][j][r] * SPLIT_INV + bb;
        const float t = tanh_fast(a);
        const f16 hi = (f16)t;
        const size_t idx = (size_t)(grow + r) * HID + gcol;
        Hh[idx] = hi;
        Hl[idx] = (f16)((t - (float)hi) * SPLIT_SCALE);  // exact residual, scaled
      }
    }
  }
}

// Y[b,t,:] = H[row,:] @ Who[64,1024]^T + bho (hi-only H: ~2^-11 rel, unamplified)
// step_fix>=0: t=step_fix, b=row (rows=4096); step_fix<0: row=t*4096+b.
__global__ __launch_bounds__(256, 2) void proj_kernel(
    const f16* __restrict__ H, const f16* __restrict__ Who,
    const float* __restrict__ bho, float* __restrict__ Y, int step_fix)
{
  __shared__ __align__(16) f16 As[128 * 64];
  __shared__ __align__(16) f16 Bs[64 * 64];
  const int lane = threadIdx.x & 63;
  const int wave = threadIdx.x >> 6;
  const int bm = blockIdx.x;
  const int sr = lane & 15;
  const int sq = lane >> 4;

  const f16* Hbase = H + (size_t)(bm * 128) * HID;

  f32x4 acc[2][4];
  const f32x4 z4 = {0.f, 0.f, 0.f, 0.f};
#pragma unroll
  for (int i = 0; i < 2; ++i)
#pragma unroll
    for (int j = 0; j < 4; ++j) acc[i][j] = z4;

  for (int kt = 0; kt < HID; kt += 64) {
#pragma unroll
    for (int u = 0; u < 4; ++u) {
      const int cidx = wave * 4 + u;
      const int mt = cidx >> 1, s = cidx & 1;
      gl2lds16(Hbase + (size_t)(mt * 16 + sr) * HID + kt + s * 32 + sq * 8, &As[cidx * 512]);
    }
#pragma unroll
    for (int u = 0; u < 2; ++u) {
      const int cidx = wave * 2 + u;
      const int nt = cidx >> 1, s = cidx & 1;
      gl2lds16(Who + (size_t)(nt * 16 + sr) * HID + kt + s * 32 + sq * 8, &Bs[cidx * 512]);
    }
    __syncthreads();
#pragma unroll
    for (int s = 0; s < 2; ++s) {
      f16x8 af[2], bfr[4];
#pragma unroll
      for (int i = 0; i < 2; ++i)
        af[i] = *(const f16x8*)&As[(((wave * 2 + i) << 1) | s) * 512 + lane * 8];
#pragma unroll
      for (int j = 0; j < 4; ++j)
        bfr[j] = *(const f16x8*)&Bs[((j << 1) | s) * 512 + lane * 8];
#pragma unroll
      for (int i = 0; i < 2; ++i)
#pragma unroll
        for (int j = 0; j < 4; ++j)
          acc[i][j] = __builtin_amdgcn_mfma_f32_16x16x32_f16(af[i], bfr[j], acc[i][j], 0, 0, 0);
    }
    __syncthreads();
  }

  const int rq = lane >> 4;
  const int cl = lane & 15;
#pragma unroll
  for (int j = 0; j < 4; ++j) {
    const int col = j * 16 + cl;
    const float bb = bho[col];
#pragma unroll
    for (int i = 0; i < 2; ++i)
#pragma unroll
      for (int r = 0; r < 4; ++r) {
        const int row = bm * 128 + wave * 32 + i * 16 + rq * 4 + r;
        int t, b;
        if (step_fix >= 0) { t = step_fix; b = row; }
        else               { t = row >> 12; b = row & 4095; }
        Y[((size_t)b * TSEQ + t) * OBS + col] = acc[i][j][r] + bb;
      }
  }
}

__global__ void cast_kernel(const float* __restrict__ x, f16* __restrict__ y, int n) {
  int i = blockIdx.x * blockDim.x + threadIdx.x;
  if (i < n) y[i] = (f16)x[i];
}

__global__ void split_kernel(const float* __restrict__ x, f16* __restrict__ hi,
                             f16* __restrict__ lo, int n) {
  int i = blockIdx.x * blockDim.x + threadIdx.x;
  if (i < n) {
    float v = x[i];
    f16 h = (f16)v;
    hi[i] = h;
    lo[i] = (f16)((v - (float)h) * SPLIT_SCALE);
  }
}

// Weff[n,k] = Whh[n,k] + sum_o Wih[n,o]*Who[o,k]  (fp32, then double-f16 split)
__global__ void prep_weff(const float* __restrict__ Whh, const float* __restrict__ Wih,
                          const float* __restrict__ Who,
                          f16* __restrict__ Wh, f16* __restrict__ Wl) {
  const int n = blockIdx.x;
  __shared__ float wih_row[OBS];
  if (threadIdx.x < OBS) wih_row[threadIdx.x] = Wih[n * OBS + threadIdx.x];
  __syncthreads();
  for (int k = threadIdx.x; k < HID; k += 256) {
    float s = Whh[(size_t)n * HID + k];
#pragma unroll 8
    for (int o = 0; o < OBS; ++o) s = fmaf(wih_row[o], Who[(size_t)o * HID + k], s);
    const size_t idx = (size_t)n * HID + k;
    f16 h = (f16)s;
    Wh[idx] = h;
    Wl[idx] = (f16)((s - (float)h) * SPLIT_SCALE);
  }
}

// W1[n,j] = sum_k Whh[n,k]*Wl2h[k,j]  (fp32, then double-f16 split)
__global__ void prep_w1(const float* __restrict__ Whh, const float* __restrict__ Wl2h,
                        f16* __restrict__ W1h, f16* __restrict__ W1l) {
  const int n = blockIdx.x, j = threadIdx.x;  // block=128
  float s = 0.f;
  for (int k = 0; k < HID; ++k) s = fmaf(Whh[(size_t)n * HID + k], Wl2h[(size_t)k * LAT + j], s);
  const size_t idx = (size_t)n * LAT + j;
  f16 h = (f16)s;
  W1h[idx] = h;
  W1l[idx] = (f16)((s - (float)h) * SPLIT_SCALE);
}

// beff[n] = bih+bhh + Wih@bho ; b1[n] = bih+bhh + Whh@bl2h
__global__ void prep_bias(const float* __restrict__ bih, const float* __restrict__ bhh,
                          const float* __restrict__ bho, const float* __restrict__ Wih,
                          const float* __restrict__ Whh, const float* __restrict__ bl2h,
                          float* __restrict__ beff, float* __restrict__ b1) {
  const int n = blockIdx.x, l = threadIdx.x;  // block=64, one wave
  float s1 = Wih[(size_t)n * OBS + l] * bho[l];
  float s2 = 0.f;
  for (int k = l; k < HID; k += 64) s2 = fmaf(Whh[(size_t)n * HID + k], bl2h[k], s2);
#pragma unroll
  for (int off = 32; off > 0; off >>= 1) {
    s1 += __shfl_down(s1, off);
    s2 += __shfl_down(s2, off);
  }
  if (l == 0) {
    const float base = bih[n] + bhh[n];
    beff[n] = base + s1;
    b1[n]   = base + s2;
  }
}

extern "C" void kernel_launch(void* const* d_in, const int* in_sizes, int n_in,
                              void* d_out, int out_size, void* d_ws, size_t ws_size,
                              hipStream_t stream) {
  (void)in_sizes; (void)n_in; (void)out_size;
  const float* z    = (const float*)d_in[0];
  const float* Wl2h = (const float*)d_in[1];
  const float* bl2h = (const float*)d_in[2];
  const float* Wih  = (const float*)d_in[3];
  const float* bih  = (const float*)d_in[4];
  const float* Whh  = (const float*)d_in[5];
  const float* bhh  = (const float*)d_in[6];
  const float* Who  = (const float*)d_in[7];
  const float* bho  = (const float*)d_in[8];
  float* Y = (float*)d_out;

  char* ws = (char*)d_ws;
  size_t off = 0;
  auto take = [&](size_t bytes) {
    char* p = ws + off;
    off = (off + bytes + 255) & ~(size_t)255;
    return p;
  };
  f16*   Weffh = (f16*)take((size_t)HID * HID * 2);
  f16*   Weffl = (f16*)take((size_t)HID * HID * 2);
  f16*   W1h   = (f16*)take((size_t)HID * LAT * 2);
  f16*   W1l   = (f16*)take((size_t)HID * LAT * 2);
  f16*   Whob  = (f16*)take((size_t)OBS * HID * 2);
  f16*   zh    = (f16*)take((size_t)B_SZ * LAT * 2);
  f16*   zl    = (f16*)take((size_t)B_SZ * LAT * 2);
  float* beff  = (float*)take(HID * 4);
  float* b1    = (float*)take(HID * 4);

  const size_t SLICE = (size_t)B_SZ * HID;  // elems per h-slice
  f16* Hlo = (f16*)take(2 * SLICE * 2);     // lo state, double-buffered
  const bool big = ws_size >= off + (size_t)TSEQ * SLICE * 2 + 256;
  f16* Hhi = (f16*)take((big ? (size_t)TSEQ : 2) * SLICE * 2);

  split_kernel<<<(B_SZ * LAT) / 256, 256, 0, stream>>>(z, zh, zl, B_SZ * LAT);
  cast_kernel<<<(OBS * HID) / 256, 256, 0, stream>>>(Who, Whob, OBS * HID);
  prep_weff<<<HID, 256, 0, stream>>>(Whh, Wih, Who, Weffh, Weffl);
  prep_w1<<<HID, LAT, 0, stream>>>(Whh, Wl2h, W1h, W1l);
  prep_bias<<<HID, 64, 0, stream>>>(bih, bhh, bho, Wih, Whh, bl2h, beff, b1);

  dim3 sgrid(B_SZ / 64, HID / 64);   // 64 x 16 = 1024 blocks = 4 blocks/CU
  // t = 0: h_1 = tanh(z @ W1^T + b1)
  f16* ph = Hhi;
  f16* pl = Hlo;
  rnn_step_split<<<sgrid, 256, 0, stream>>>(zh, zl, W1h, W1l, b1, ph, pl, LAT);
  if (!big) proj_kernel<<<B_SZ / 128, 256, 0, stream>>>(ph, Whob, bho, Y, 0);
  for (int t = 1; t < TSEQ; ++t) {
    f16* ch  = big ? (Hhi + (size_t)t * SLICE) : (Hhi + (size_t)(t & 1) * SLICE);
    f16* cle = Hlo + (size_t)(t & 1) * SLICE;
    rnn_step_split<<<sgrid, 256, 0, stream>>>(ph, pl, Weffh, Weffl, beff, ch, cle, HID);
    if (!big) proj_kernel<<<B_SZ / 128, 256, 0, stream>>>(ch, Whob, bho, Y, t);
    ph = ch;
    pl = cle;
  }
  if (big) proj_kernel<<<(TSEQ * B_SZ) / 128, 256, 0, stream>>>(Hhi, Whob, bho, Y, -1);
}

// Round 7
// 3977.916 us; speedup vs baseline: 1.5395x; 1.5395x over previous
//
#include <hip/hip_runtime.h>
#include <hip/hip_bf16.h>
#include <stdint.h>

typedef _Float16 f16;
typedef _Float16 f16x8 __attribute__((ext_vector_type(8)));
typedef float f32x4 __attribute__((ext_vector_type(4)));

#define B_SZ 4096
#define HID  1024
#define LAT  128
#define OBS  64
#define TSEQ 70
#define SPLIT_SCALE 2048.0f        // 2^11
#define SPLIT_INV   (1.0f / 2048.0f)

// ---- fragment-tiled global layout -----------------------------------------
// Matrix [R rows x K cols] stored as chunks of 16 rows x 32 cols; chunk
// (rg, kc) at flat offset ((rg*(K/32))+kc)*512. Within a chunk, element
// (r,k) sits at ((k>>3)&3)*128 + (r&15)*8 + (k&7)  — i.e. lane L's 16 B MFMA
// fragment (m=L&15, k=(L>>4)*8..+8) is bytes [L*16, L*16+16).
__device__ __forceinline__ size_t tidx(int row, int k, int K) {
  return (size_t)((row >> 4) * (K >> 5) + (k >> 5)) * 512
       + ((k >> 3) & 3) * 128 + (row & 15) * 8 + (k & 7);
}

// direct global->LDS: PER-LANE global vaddr (caller adds lane*8 f16!),
// wave-uniform LDS base (HW adds lane*16 on the LDS side) [m104/m108].
// R6 bug: passed wave-uniform global ptr -> all lanes fetched same 16 B.
__device__ __forceinline__ void gl2lds16(const void* g, void* l) {
  __builtin_amdgcn_global_load_lds(
      (const __attribute__((address_space(1))) void*)g,
      (__attribute__((address_space(3))) void*)l, 16, 0, 0);
}

__device__ __forceinline__ float tanh_fast(float x) {
  float e = __expf(2.0f * x);          // inf-safe: x>>0 -> 1, x<<0 -> -1
  return 1.0f - 2.0f / (e + 1.0f);
}

// H = tanh(A @ W^T + bias), A,W in double-f16 (hi + lo*2^-11 ~ 22-bit capture):
//   acc0 = A0*W0 ; acc1 = A0*W1' + A1'*W0  (primes pre-scaled 2^11)
//   a = acc0 + acc1*2^-11   (dropped A1*W1 term is 2^-22 rel)
// All matrix operands in fragment-tiled global layout (see tidx).
// 128x128 tile, BK=32, single-buffered LDS (32 KB) -> 2 blocks/CU,
// two barriers per K-iter (replay-safe R5 structure). Staging: each chunk is
// one fully-coalesced 1 KB burst (lane L fetches bytes [L*16,+16)).
__global__ __launch_bounds__(256, 2) void rnn_step_split(
    const f16* __restrict__ Ah, const f16* __restrict__ Al,
    const f16* __restrict__ Wh, const f16* __restrict__ Wl,
    const float* __restrict__ bias,
    f16* __restrict__ Hh, f16* __restrict__ Hl, int K)
{
  __shared__ __align__(16) f16 sAh[128 * 32];
  __shared__ __align__(16) f16 sAl[128 * 32];
  __shared__ __align__(16) f16 sWh[128 * 32];
  __shared__ __align__(16) f16 sWl[128 * 32];

  const int lane = threadIdx.x & 63;
  const int wave = threadIdx.x >> 6;
  const int bm = blockIdx.x;      // 32  (M/128)
  const int bn = blockIdx.y;      // 8   (1024/128)
  const int wr = wave >> 1;
  const int wc = wave & 1;
  const int lo8 = lane * 8;       // per-lane 16 B offset within a chunk
  const int kc = K >> 5;          // chunks per row-group

  f32x4 acc0[4][4], acc1[4][4];
  const f32x4 z4 = {0.f, 0.f, 0.f, 0.f};
#pragma unroll
  for (int i = 0; i < 4; ++i)
#pragma unroll
    for (int j = 0; j < 4; ++j) { acc0[i][j] = z4; acc1[i][j] = z4; }

  for (int it = 0; it < kc; ++it) {
    // stage: wave w loads row-chunks 2w, 2w+1 of all 4 matrices (8 x 1KB bursts)
#pragma unroll
    for (int u = 0; u < 2; ++u) {
      const int mt = wave * 2 + u;
      const size_t ga = (size_t)((bm * 8 + mt) * kc + it) * 512 + lo8;
      const size_t gw = (size_t)((bn * 8 + mt) * kc + it) * 512 + lo8;
      gl2lds16(Ah + ga, &sAh[mt * 512]);
      gl2lds16(Al + ga, &sAl[mt * 512]);
      gl2lds16(Wh + gw, &sWh[mt * 512]);
      gl2lds16(Wl + gw, &sWl[mt * 512]);
    }
    __syncthreads();  // vmcnt(0) drain: all chunks landed

    f16x8 vah[4], val[4], vwh[4], vwl[4];
#pragma unroll
    for (int i = 0; i < 4; ++i) {
      vah[i] = *(const f16x8*)&sAh[(wr * 4 + i) * 512 + lo8];
      val[i] = *(const f16x8*)&sAl[(wr * 4 + i) * 512 + lo8];
      vwh[i] = *(const f16x8*)&sWh[(wc * 4 + i) * 512 + lo8];
      vwl[i] = *(const f16x8*)&sWl[(wc * 4 + i) * 512 + lo8];
    }
#pragma unroll
    for (int i = 0; i < 4; ++i)
#pragma unroll
      for (int j = 0; j < 4; ++j) {
        acc0[i][j] = __builtin_amdgcn_mfma_f32_16x16x32_f16(vah[i], vwh[j], acc0[i][j], 0, 0, 0);
        acc1[i][j] = __builtin_amdgcn_mfma_f32_16x16x32_f16(vah[i], vwl[j], acc1[i][j], 0, 0, 0);
        acc1[i][j] = __builtin_amdgcn_mfma_f32_16x16x32_f16(val[i], vwh[j], acc1[i][j], 0, 0, 0);
      }
    __syncthreads();  // all ds_reads done before next stage overwrites
  }

  // C/D layout: col=lane&15, row=(lane>>4)*4+reg  [m89-verified]; H stored tiled
  const int rq = lane >> 4;
  const int cl = lane & 15;
#pragma unroll
  for (int j = 0; j < 4; ++j) {
    const int gcol = bn * 128 + wc * 64 + j * 16 + cl;
    const float bb = bias[gcol];
#pragma unroll
    for (int i = 0; i < 4; ++i) {
      const int grow = bm * 128 + wr * 64 + i * 16 + rq * 4;
#pragma unroll
      for (int r = 0; r < 4; ++r) {
        const float a = acc0[i][j][r] + acc1[i][j][r] * SPLIT_INV + bb;
        const float t = tanh_fast(a);
        const f16 hi = (f16)t;
        const size_t idx = tidx(grow + r, gcol, HID);
        Hh[idx] = hi;
        Hl[idx] = (f16)((t - (float)hi) * SPLIT_SCALE);  // exact residual, scaled
      }
    }
  }
}

// Y[b,t,:] = H[row,:] @ Who[64,1024]^T + bho. H, Who fragment-tiled (hi-only H).
// step_fix>=0: t=step_fix, b=row (rows=4096); step_fix<0: row=t*4096+b.
__global__ __launch_bounds__(256, 2) void proj_kernel(
    const f16* __restrict__ H, const f16* __restrict__ Who,
    const float* __restrict__ bho, float* __restrict__ Y, int step_fix)
{
  __shared__ __align__(16) f16 As[128 * 64];
  __shared__ __align__(16) f16 Bs[64 * 64];
  const int lane = threadIdx.x & 63;
  const int wave = threadIdx.x >> 6;
  const int bm = blockIdx.x;
  const int lo8 = lane * 8;

  f32x4 acc[2][4];
  const f32x4 z4 = {0.f, 0.f, 0.f, 0.f};
#pragma unroll
  for (int i = 0; i < 2; ++i)
#pragma unroll
    for (int j = 0; j < 4; ++j) acc[i][j] = z4;

  for (int kt = 0; kt < HID; kt += 64) {
    const int kch = kt >> 5;
    // A: row-groups bm*8 .. bm*8+7, two k-chunks each; 16 chunks, 4/wave
#pragma unroll
    for (int u = 0; u < 4; ++u) {
      const int cidx = wave * 4 + u;
      const int mt = cidx >> 1, s = cidx & 1;
      gl2lds16(H + (size_t)((bm * 8 + mt) * 32 + kch + s) * 512 + lo8, &As[cidx * 512]);
    }
    // Who: row-groups 0..3, two k-chunks; 8 chunks, 2/wave
#pragma unroll
    for (int u = 0; u < 2; ++u) {
      const int cidx = wave * 2 + u;
      const int nt = cidx >> 1, s = cidx & 1;
      gl2lds16(Who + (size_t)(nt * 32 + kch + s) * 512 + lo8, &Bs[cidx * 512]);
    }
    __syncthreads();
#pragma unroll
    for (int s = 0; s < 2; ++s) {
      f16x8 af[2], bfr[4];
#pragma unroll
      for (int i = 0; i < 2; ++i)
        af[i] = *(const f16x8*)&As[(((wave * 2 + i) << 1) | s) * 512 + lo8];
#pragma unroll
      for (int j = 0; j < 4; ++j)
        bfr[j] = *(const f16x8*)&Bs[((j << 1) | s) * 512 + lo8];
#pragma unroll
      for (int i = 0; i < 2; ++i)
#pragma unroll
        for (int j = 0; j < 4; ++j)
          acc[i][j] = __builtin_amdgcn_mfma_f32_16x16x32_f16(af[i], bfr[j], acc[i][j], 0, 0, 0);
    }
    __syncthreads();
  }

  const int rq = lane >> 4;
  const int cl = lane & 15;
#pragma unroll
  for (int j = 0; j < 4; ++j) {
    const int col = j * 16 + cl;
    const float bb = bho[col];
#pragma unroll
    for (int i = 0; i < 2; ++i)
#pragma unroll
      for (int r = 0; r < 4; ++r) {
        const int row = bm * 128 + wave * 32 + i * 16 + rq * 4 + r;
        int t, b;
        if (step_fix >= 0) { t = step_fix; b = row; }
        else               { t = row >> 12; b = row & 4095; }
        Y[((size_t)b * TSEQ + t) * OBS + col] = acc[i][j][r] + bb;
      }
  }
}

// fp32 [R x K] row-major -> tiled f16 (cast only; for Who)
__global__ void cast_tiled_kernel(const float* __restrict__ x, f16* __restrict__ y,
                                  int K, int n) {
  int i = blockIdx.x * blockDim.x + threadIdx.x;
  if (i < n) y[tidx(i / K, i % K, K)] = (f16)x[i];
}

// fp32 [R x K] row-major -> tiled double-f16 split (for z)
__global__ void split_tiled_kernel(const float* __restrict__ x, f16* __restrict__ hi,
                                   f16* __restrict__ lo, int K, int n) {
  int i = blockIdx.x * blockDim.x + threadIdx.x;
  if (i < n) {
    float v = x[i];
    f16 h = (f16)v;
    size_t o = tidx(i / K, i % K, K);
    hi[o] = h;
    lo[o] = (f16)((v - (float)h) * SPLIT_SCALE);
  }
}

// Weff[n,k] = Whh[n,k] + sum_o Wih[n,o]*Who[o,k]  (fp32, then tiled split)
__global__ void prep_weff(const float* __restrict__ Whh, const float* __restrict__ Wih,
                          const float* __restrict__ Who,
                          f16* __restrict__ Wh, f16* __restrict__ Wl) {
  const int n = blockIdx.x;
  __shared__ float wih_row[OBS];
  if (threadIdx.x < OBS) wih_row[threadIdx.x] = Wih[n * OBS + threadIdx.x];
  __syncthreads();
  for (int k = threadIdx.x; k < HID; k += 256) {
    float s = Whh[(size_t)n * HID + k];
#pragma unroll 8
    for (int o = 0; o < OBS; ++o) s = fmaf(wih_row[o], Who[(size_t)o * HID + k], s);
    const size_t idx = tidx(n, k, HID);
    f16 h = (f16)s;
    Wh[idx] = h;
    Wl[idx] = (f16)((s - (float)h) * SPLIT_SCALE);
  }
}

// W1[n,j] = sum_k Whh[n,k]*Wl2h[k,j]  (fp32, then tiled split)
__global__ void prep_w1(const float* __restrict__ Whh, const float* __restrict__ Wl2h,
                        f16* __restrict__ W1h, f16* __restrict__ W1l) {
  const int n = blockIdx.x, j = threadIdx.x;  // block=128
  float s = 0.f;
  for (int k = 0; k < HID; ++k) s = fmaf(Whh[(size_t)n * HID + k], Wl2h[(size_t)k * LAT + j], s);
  const size_t idx = tidx(n, j, LAT);
  f16 h = (f16)s;
  W1h[idx] = h;
  W1l[idx] = (f16)((s - (float)h) * SPLIT_SCALE);
}

// beff[n] = bih+bhh + Wih@bho ; b1[n] = bih+bhh + Whh@bl2h
__global__ void prep_bias(const float* __restrict__ bih, const float* __restrict__ bhh,
                          const float* __restrict__ bho, const float* __restrict__ Wih,
                          const float* __restrict__ Whh, const float* __restrict__ bl2h,
                          float* __restrict__ beff, float* __restrict__ b1) {
  const int n = blockIdx.x, l = threadIdx.x;  // block=64, one wave
  float s1 = Wih[(size_t)n * OBS + l] * bho[l];
  float s2 = 0.f;
  for (int k = l; k < HID; k += 64) s2 = fmaf(Whh[(size_t)n * HID + k], bl2h[k], s2);
#pragma unroll
  for (int off = 32; off > 0; off >>= 1) {
    s1 += __shfl_down(s1, off);
    s2 += __shfl_down(s2, off);
  }
  if (l == 0) {
    const float base = bih[n] + bhh[n];
    beff[n] = base + s1;
    b1[n]   = base + s2;
  }
}

extern "C" void kernel_launch(void* const* d_in, const int* in_sizes, int n_in,
                              void* d_out, int out_size, void* d_ws, size_t ws_size,
                              hipStream_t stream) {
  (void)in_sizes; (void)n_in; (void)out_size;
  const float* z    = (const float*)d_in[0];
  const float* Wl2h = (const float*)d_in[1];
  const float* bl2h = (const float*)d_in[2];
  const float* Wih  = (const float*)d_in[3];
  const float* bih  = (const float*)d_in[4];
  const float* Whh  = (const float*)d_in[5];
  const float* bhh  = (const float*)d_in[6];
  const float* Who  = (const float*)d_in[7];
  const float* bho  = (const float*)d_in[8];
  float* Y = (float*)d_out;

  char* ws = (char*)d_ws;
  size_t off = 0;
  auto take = [&](size_t bytes) {
    char* p = ws + off;
    off = (off + bytes + 255) & ~(size_t)255;
    return p;
  };
  f16*   Weffh = (f16*)take((size_t)HID * HID * 2);
  f16*   Weffl = (f16*)take((size_t)HID * HID * 2);
  f16*   W1h   = (f16*)take((size_t)HID * LAT * 2);
  f16*   W1l   = (f16*)take((size_t)HID * LAT * 2);
  f16*   Whob  = (f16*)take((size_t)OBS * HID * 2);
  f16*   zh    = (f16*)take((size_t)B_SZ * LAT * 2);
  f16*   zl    = (f16*)take((size_t)B_SZ * LAT * 2);
  float* beff  = (float*)take(HID * 4);
  float* b1    = (float*)take(HID * 4);

  const size_t SLICE = (size_t)B_SZ * HID;  // elems per h-slice
  f16* Hlo = (f16*)take(2 * SLICE * 2);     // lo state, double-buffered
  const bool big = ws_size >= off + (size_t)TSEQ * SLICE * 2 + 256;
  f16* Hhi = (f16*)take((big ? (size_t)TSEQ : 2) * SLICE * 2);

  split_tiled_kernel<<<(B_SZ * LAT) / 256, 256, 0, stream>>>(z, zh, zl, LAT, B_SZ * LAT);
  cast_tiled_kernel<<<(OBS * HID) / 256, 256, 0, stream>>>(Who, Whob, HID, OBS * HID);
  prep_weff<<<HID, 256, 0, stream>>>(Whh, Wih, Who, Weffh, Weffl);
  prep_w1<<<HID, LAT, 0, stream>>>(Whh, Wl2h, W1h, W1l);
  prep_bias<<<HID, 64, 0, stream>>>(bih, bhh, bho, Wih, Whh, bl2h, beff, b1);

  dim3 sgrid(B_SZ / 128, HID / 128);   // 32 x 8 = 256 blocks = 2 blocks/CU (32 KB LDS)
  // t = 0: h_1 = tanh(z @ W1^T + b1)
  f16* ph = Hhi;
  f16* pl = Hlo;
  rnn_step_split<<<sgrid, 256, 0, stream>>>(zh, zl, W1h, W1l, b1, ph, pl, LAT);
  if (!big) proj_kernel<<<B_SZ / 128, 256, 0, stream>>>(ph, Whob, bho, Y, 0);
  for (int t = 1; t < TSEQ; ++t) {
    f16* ch  = big ? (Hhi + (size_t)t * SLICE) : (Hhi + (size_t)(t & 1) * SLICE);
    f16* cle = Hlo + (size_t)(t & 1) * SLICE;
    rnn_step_split<<<sgrid, 256, 0, stream>>>(ph, pl, Weffh, Weffl, beff, ch, cle, HID);
    if (!big) proj_kernel<<<B_SZ / 128, 256, 0, stream>>>(ch, Whob, bho, Y, t);
    ph = ch;
    pl = cle;
  }
  if (big) proj_kernel<<<(TSEQ * B_SZ) / 128, 256, 0, stream>>>(Hhi, Whob, bho, Y, -1);
}

// Round 8
// 2412.137 us; speedup vs baseline: 2.5388x; 1.6491x over previous
//
#include <hip/hip_runtime.h>
#include <hip/hip_bf16.h>
#include <stdint.h>

typedef _Float16 f16;
typedef _Float16 f16x8 __attribute__((ext_vector_type(8)));
typedef float f32x4 __attribute__((ext_vector_type(4)));

#define B_SZ 4096
#define HID  1024
#define LAT  128
#define OBS  64
#define TSEQ 70
#define SPLIT_SCALE 2048.0f        // 2^11
#define SPLIT_INV   (1.0f / 2048.0f)

// ---- fragment-tiled global layout -----------------------------------------
// Matrix [R rows x K cols] stored as chunks of 16 rows x 32 cols; chunk
// (rg, kc) at flat offset ((rg*(K/32))+kc)*512. Within a chunk, element
// (r,k) sits at ((k>>3)&3)*128 + (r&15)*8 + (k&7)  — lane L's 16 B MFMA
// fragment (m=L&15, k=(L>>4)*8..+8) is bytes [L*16, L*16+16).
__device__ __forceinline__ size_t tidx(int row, int k, int K) {
  return (size_t)((row >> 4) * (K >> 5) + (k >> 5)) * 512
       + ((k >> 3) & 3) * 128 + (row & 15) * 8 + (k & 7);
}

// direct global->LDS: PER-LANE global vaddr (caller adds lane*8 f16!),
// wave-uniform LDS base (HW adds lane*16 on the LDS side) [m104/m108].
__device__ __forceinline__ void gl2lds16(const void* g, void* l) {
  __builtin_amdgcn_global_load_lds(
      (const __attribute__((address_space(1))) void*)g,
      (__attribute__((address_space(3))) void*)l, 16, 0, 0);
}

__device__ __forceinline__ float tanh_fast(float x) {
  float e = __expf(2.0f * x);          // inf-safe: x>>0 -> 1, x<<0 -> -1
  return 1.0f - 2.0f / (e + 1.0f);
}

// H = tanh(A @ W^T + bias), double-f16 operands (hi + lo*2^-11 ~ 22-bit):
//   acc0 = A0*W0 ; acc1 = A0*W1' + A1'*W0 ; a = acc0 + acc1*2^-11.
// R8: 128x64 tile (MxN), BK=64 -> grid 32x16 = 512 blocks = 2 blocks/CU
// (real co-residency: R7's grid was 256 = 1/CU, zero overlap). LDS 48 KB,
// single-buffered, two barriers per K-iter (replay-safe). Wave w owns rows
// [w*32,+32). Linear block id = bm + 32*bn -> XCD = bm%8: H rows stay
// XCD-local step-to-step (A staging L2-hit).
__global__ __launch_bounds__(256, 2) void rnn_step_split(
    const f16* __restrict__ Ah, const f16* __restrict__ Al,
    const f16* __restrict__ Wh, const f16* __restrict__ Wl,
    const float* __restrict__ bias,
    f16* __restrict__ Hh, f16* __restrict__ Hl, int K)
{
  __shared__ __align__(16) f16 sAh[16 * 512];  // 8 rg x 2 kc
  __shared__ __align__(16) f16 sAl[16 * 512];
  __shared__ __align__(16) f16 sWh[8 * 512];   // 4 nrg x 2 kc
  __shared__ __align__(16) f16 sWl[8 * 512];

  const int lane = threadIdx.x & 63;
  const int wave = threadIdx.x >> 6;
  const int bm = blockIdx.x;      // 32  (M/128)
  const int bn = blockIdx.y;      // 16  (1024/64)
  const int lo8 = lane * 8;       // per-lane 16 B offset within a chunk
  const int kc = K >> 5;          // 32-col chunks per row-group

  f32x4 acc0[2][4], acc1[2][4];
  const f32x4 z4 = {0.f, 0.f, 0.f, 0.f};
#pragma unroll
  for (int i = 0; i < 2; ++i)
#pragma unroll
    for (int j = 0; j < 4; ++j) { acc0[i][j] = z4; acc1[i][j] = z4; }

  const int nk = K >> 6;          // BK = 64 = 2 chunks

  for (int it = 0; it < nk; ++it) {
    // stage: per wave, A rgs {2w,2w+1} x 2 kc x hi/lo = 8 loads; W 2 chunks x2 = 4
#pragma unroll
    for (int u = 0; u < 2; ++u) {
      const int rg = wave * 2 + u;
#pragma unroll
      for (int s = 0; s < 2; ++s) {
        const size_t ga = (size_t)((bm * 8 + rg) * kc + (it * 2 + s)) * 512 + lo8;
        gl2lds16(Ah + ga, &sAh[(rg * 2 + s) * 512]);
        gl2lds16(Al + ga, &sAl[(rg * 2 + s) * 512]);
      }
    }
#pragma unroll
    for (int u = 0; u < 2; ++u) {
      const int c = wave * 2 + u;          // 8 W chunks, 2/wave
      const int nrg = c >> 1, s = c & 1;
      const size_t gw = (size_t)((bn * 4 + nrg) * kc + (it * 2 + s)) * 512 + lo8;
      gl2lds16(Wh + gw, &sWh[c * 512]);
      gl2lds16(Wl + gw, &sWl[c * 512]);
    }
    __syncthreads();  // vmcnt(0) drain: all chunks landed

#pragma unroll
    for (int s = 0; s < 2; ++s) {
      f16x8 vah[2], val[2], vwh[4], vwl[4];
#pragma unroll
      for (int i = 0; i < 2; ++i) {
        vah[i] = *(const f16x8*)&sAh[((wave * 2 + i) * 2 + s) * 512 + lo8];
        val[i] = *(const f16x8*)&sAl[((wave * 2 + i) * 2 + s) * 512 + lo8];
      }
#pragma unroll
      for (int j = 0; j < 4; ++j) {
        vwh[j] = *(const f16x8*)&sWh[(j * 2 + s) * 512 + lo8];
        vwl[j] = *(const f16x8*)&sWl[(j * 2 + s) * 512 + lo8];
      }
#pragma unroll
      for (int i = 0; i < 2; ++i)
#pragma unroll
        for (int j = 0; j < 4; ++j) {
          acc0[i][j] = __builtin_amdgcn_mfma_f32_16x16x32_f16(vah[i], vwh[j], acc0[i][j], 0, 0, 0);
          acc1[i][j] = __builtin_amdgcn_mfma_f32_16x16x32_f16(vah[i], vwl[j], acc1[i][j], 0, 0, 0);
          acc1[i][j] = __builtin_amdgcn_mfma_f32_16x16x32_f16(val[i], vwh[j], acc1[i][j], 0, 0, 0);
        }
    }
    __syncthreads();  // all ds_reads done before next stage overwrites
  }

  // C/D layout: col=lane&15, row=(lane>>4)*4+reg  [m89-verified]; H stored tiled
  const int rq = lane >> 4;
  const int cl = lane & 15;
#pragma unroll
  for (int j = 0; j < 4; ++j) {
    const int gcol = bn * 64 + j * 16 + cl;
    const float bb = bias[gcol];
#pragma unroll
    for (int i = 0; i < 2; ++i) {
      const int grow = bm * 128 + wave * 32 + i * 16 + rq * 4;
#pragma unroll
      for (int r = 0; r < 4; ++r) {
        const float a = acc0[i][j][r] + acc1[i][j][r] * SPLIT_INV + bb;
        const float t = tanh_fast(a);
        const f16 hi = (f16)t;
        const size_t idx = tidx(grow + r, gcol, HID);
        Hh[idx] = hi;
        Hl[idx] = (f16)((t - (float)hi) * SPLIT_SCALE);  // exact residual, scaled
      }
    }
  }
}

// Y[b,t,:] = H[row,:] @ Who[64,1024]^T + bho over a contiguous ring of hi
// slices. row = s*4096 + b, t = t0 + s. H, Who fragment-tiled; grid = rows/128.
__global__ __launch_bounds__(256, 2) void proj_kernel(
    const f16* __restrict__ H, const f16* __restrict__ Who,
    const float* __restrict__ bho, float* __restrict__ Y, int t0)
{
  __shared__ __align__(16) f16 As[128 * 64];
  __shared__ __align__(16) f16 Bs[64 * 64];
  const int lane = threadIdx.x & 63;
  const int wave = threadIdx.x >> 6;
  const int bm = blockIdx.x;
  const int lo8 = lane * 8;

  f32x4 acc[2][4];
  const f32x4 z4 = {0.f, 0.f, 0.f, 0.f};
#pragma unroll
  for (int i = 0; i < 2; ++i)
#pragma unroll
    for (int j = 0; j < 4; ++j) acc[i][j] = z4;

  for (int kt = 0; kt < HID; kt += 64) {
    const int kch = kt >> 5;
    // A: row-groups bm*8 .. +7, two k-chunks each; 16 chunks, 4/wave
#pragma unroll
    for (int u = 0; u < 4; ++u) {
      const int cidx = wave * 4 + u;
      const int mt = cidx >> 1, s = cidx & 1;
      gl2lds16(H + (size_t)((bm * 8 + mt) * 32 + kch + s) * 512 + lo8, &As[cidx * 512]);
    }
    // Who: row-groups 0..3, two k-chunks; 8 chunks, 2/wave
#pragma unroll
    for (int u = 0; u < 2; ++u) {
      const int cidx = wave * 2 + u;
      const int nt = cidx >> 1, s = cidx & 1;
      gl2lds16(Who + (size_t)(nt * 32 + kch + s) * 512 + lo8, &Bs[cidx * 512]);
    }
    __syncthreads();
#pragma unroll
    for (int s = 0; s < 2; ++s) {
      f16x8 af[2], bfr[4];
#pragma unroll
      for (int i = 0; i < 2; ++i)
        af[i] = *(const f16x8*)&As[(((wave * 2 + i) << 1) | s) * 512 + lo8];
#pragma unroll
      for (int j = 0; j < 4; ++j)
        bfr[j] = *(const f16x8*)&Bs[((j << 1) | s) * 512 + lo8];
#pragma unroll
      for (int i = 0; i < 2; ++i)
#pragma unroll
        for (int j = 0; j < 4; ++j)
          acc[i][j] = __builtin_amdgcn_mfma_f32_16x16x32_f16(af[i], bfr[j], acc[i][j], 0, 0, 0);
    }
    __syncthreads();
  }

  const int rq = lane >> 4;
  const int cl = lane & 15;
#pragma unroll
  for (int j = 0; j < 4; ++j) {
    const int col = j * 16 + cl;
    const float bb = bho[col];
#pragma unroll
    for (int i = 0; i < 2; ++i)
#pragma unroll
      for (int r = 0; r < 4; ++r) {
        const int row = bm * 128 + wave * 32 + i * 16 + rq * 4 + r;
        const int t = t0 + (row >> 12);
        const int b = row & 4095;
        Y[((size_t)b * TSEQ + t) * OBS + col] = acc[i][j][r] + bb;
      }
  }
}

// fp32 [R x K] row-major -> tiled f16 (cast only; for Who)
__global__ void cast_tiled_kernel(const float* __restrict__ x, f16* __restrict__ y,
                                  int K, int n) {
  int i = blockIdx.x * blockDim.x + threadIdx.x;
  if (i < n) y[tidx(i / K, i % K, K)] = (f16)x[i];
}

// fp32 [R x K] row-major -> tiled double-f16 split (for z)
__global__ void split_tiled_kernel(const float* __restrict__ x, f16* __restrict__ hi,
                                   f16* __restrict__ lo, int K, int n) {
  int i = blockIdx.x * blockDim.x + threadIdx.x;
  if (i < n) {
    float v = x[i];
    f16 h = (f16)v;
    size_t o = tidx(i / K, i % K, K);
    hi[o] = h;
    lo[o] = (f16)((v - (float)h) * SPLIT_SCALE);
  }
}

// Weff[n,k] = Whh[n,k] + sum_o Wih[n,o]*Who[o,k]  (fp32, then tiled split)
__global__ void prep_weff(const float* __restrict__ Whh, const float* __restrict__ Wih,
                          const float* __restrict__ Who,
                          f16* __restrict__ Wh, f16* __restrict__ Wl) {
  const int n = blockIdx.x;
  __shared__ float wih_row[OBS];
  if (threadIdx.x < OBS) wih_row[threadIdx.x] = Wih[n * OBS + threadIdx.x];
  __syncthreads();
  for (int k = threadIdx.x; k < HID; k += 256) {
    float s = Whh[(size_t)n * HID + k];
#pragma unroll 8
    for (int o = 0; o < OBS; ++o) s = fmaf(wih_row[o], Who[(size_t)o * HID + k], s);
    const size_t idx = tidx(n, k, HID);
    f16 h = (f16)s;
    Wh[idx] = h;
    Wl[idx] = (f16)((s - (float)h) * SPLIT_SCALE);
  }
}

// W1[n,j] = sum_k Whh[n,k]*Wl2h[k,j]  (fp32, then tiled split)
__global__ void prep_w1(const float* __restrict__ Whh, const float* __restrict__ Wl2h,
                        f16* __restrict__ W1h, f16* __restrict__ W1l) {
  const int n = blockIdx.x, j = threadIdx.x;  // block=128
  float s = 0.f;
  for (int k = 0; k < HID; ++k) s = fmaf(Whh[(size_t)n * HID + k], Wl2h[(size_t)k * LAT + j], s);
  const size_t idx = tidx(n, j, LAT);
  f16 h = (f16)s;
  W1h[idx] = h;
  W1l[idx] = (f16)((s - (float)h) * SPLIT_SCALE);
}

// beff[n] = bih+bhh + Wih@bho ; b1[n] = bih+bhh + Whh@bl2h
__global__ void prep_bias(const float* __restrict__ bih, const float* __restrict__ bhh,
                          const float* __restrict__ bho, const float* __restrict__ Wih,
                          const float* __restrict__ Whh, const float* __restrict__ bl2h,
                          float* __restrict__ beff, float* __restrict__ b1) {
  const int n = blockIdx.x, l = threadIdx.x;  // block=64, one wave
  float s1 = Wih[(size_t)n * OBS + l] * bho[l];
  float s2 = 0.f;
  for (int k = l; k < HID; k += 64) s2 = fmaf(Whh[(size_t)n * HID + k], bl2h[k], s2);
#pragma unroll
  for (int off = 32; off > 0; off >>= 1) {
    s1 += __shfl_down(s1, off);
    s2 += __shfl_down(s2, off);
  }
  if (l == 0) {
    const float base = bih[n] + bhh[n];
    beff[n] = base + s1;
    b1[n]   = base + s2;
  }
}

extern "C" void kernel_launch(void* const* d_in, const int* in_sizes, int n_in,
                              void* d_out, int out_size, void* d_ws, size_t ws_size,
                              hipStream_t stream) {
  (void)in_sizes; (void)n_in; (void)out_size; (void)ws_size;
  const float* z    = (const float*)d_in[0];
  const float* Wl2h = (const float*)d_in[1];
  const float* bl2h = (const float*)d_in[2];
  const float* Wih  = (const float*)d_in[3];
  const float* bih  = (const float*)d_in[4];
  const float* Whh  = (const float*)d_in[5];
  const float* bhh  = (const float*)d_in[6];
  const float* Who  = (const float*)d_in[7];
  const float* bho  = (const float*)d_in[8];
  float* Y = (float*)d_out;

  char* ws = (char*)d_ws;
  size_t off = 0;
  auto take = [&](size_t bytes) {
    char* p = ws + off;
    off = (off + bytes + 255) & ~(size_t)255;
    return p;
  };
  f16*   Weffh = (f16*)take((size_t)HID * HID * 2);
  f16*   Weffl = (f16*)take((size_t)HID * HID * 2);
  f16*   W1h   = (f16*)take((size_t)HID * LAT * 2);
  f16*   W1l   = (f16*)take((size_t)HID * LAT * 2);
  f16*   Whob  = (f16*)take((size_t)OBS * HID * 2);
  f16*   zh    = (f16*)take((size_t)B_SZ * LAT * 2);
  f16*   zl    = (f16*)take((size_t)B_SZ * LAT * 2);
  float* beff  = (float*)take(HID * 4);
  float* b1    = (float*)take(HID * 4);

  const size_t S = (size_t)B_SZ * HID;     // elems per h-slice
  f16* Hlo  = (f16*)take(2 * S * 2);       // lo state, double-buffered
  f16* ring = (f16*)take(8 * S * 2);       // hi state, ring of 8 (~67 MB; ws=280 MB)

  split_tiled_kernel<<<(B_SZ * LAT) / 256, 256, 0, stream>>>(z, zh, zl, LAT, B_SZ * LAT);
  cast_tiled_kernel<<<(OBS * HID) / 256, 256, 0, stream>>>(Who, Whob, HID, OBS * HID);
  prep_weff<<<HID, 256, 0, stream>>>(Whh, Wih, Who, Weffh, Weffl);
  prep_w1<<<HID, LAT, 0, stream>>>(Whh, Wl2h, W1h, W1l);
  prep_bias<<<HID, 64, 0, stream>>>(bih, bhh, bho, Wih, Whh, bl2h, beff, b1);

  dim3 sgrid(B_SZ / 128, HID / 64);   // 32 x 16 = 512 blocks = 2 blocks/CU
  // t = 0: h_1 = tanh(z @ W1^T + b1) -> ring slice 0
  rnn_step_split<<<sgrid, 256, 0, stream>>>(zh, zl, W1h, W1l, b1, ring, Hlo, LAT);
  for (int t = 1; t < TSEQ; ++t) {
    if ((t & 7) == 0)  // ring full: project slices t-8..t-1 before overwriting
      proj_kernel<<<(8 * B_SZ) / 128, 256, 0, stream>>>(ring, Whob, bho, Y, t - 8);
    rnn_step_split<<<sgrid, 256, 0, stream>>>(
        ring + (size_t)((t - 1) & 7) * S, Hlo + (size_t)((t - 1) & 1) * S,
        Weffh, Weffl, beff,
        ring + (size_t)(t & 7) * S, Hlo + (size_t)(t & 1) * S, HID);
  }
  // tail: t = 64..69 live in slices 0..5
  proj_kernel<<<(6 * B_SZ) / 128, 256, 0, stream>>>(ring, Whob, bho, Y, 64);
}